// Round 3
// baseline (231.352 us; speedup 1.0000x reference)
//
#include <hip/hip_runtime.h>

// y[..., 2k]   = T[k][0][0]*x[2k] + T[k][0][1]*x[2k+1]
// y[..., 2k+1] = T[k][1][0]*x[2k] + T[k][1][1]*x[2k+1]
//
// R0 skeleton (fastest so far): thread owns one float4-column p, twiddles
// hoisted to registers, rows streamed with all loads batched up front.
// Evidence so far:
//   R1: grid-stride sweep -> compiler collapsed MLP (VGPR=28) -> 2.1 TB/s. Never again.
//   R2: plain loads/stores -> slightly SLOWER than NT despite halved FETCH_SIZE
//       (L3 served x/2). Faster-with-more-HBM-bytes => NOT BW-bound; limiter is
//       latency/ramp. Keep NT for both streams (no cache pollution, no RFO).
// This round: ROWS_PER_BLOCK 8 -> 16, 2048 blocks = exactly 8/CU, one
// residency generation. Halves block launch/tail overhead and twiddle
// reloads; 16-deep per-wave load burst. VGPR ~85 -> 6 waves/SIMD (plenty:
// in-flight bytes >> latency-BW product).

typedef float f4 __attribute__((ext_vector_type(4)));

#define ROW4 1024            // 4096 floats / 4 per row
#define ROWS_PER_BLOCK 16

__global__ __launch_bounds__(256) void butterfly_kernel(
    const f4* __restrict__ x,
    const f4* __restrict__ tw,   // tw[k] = {t00,t01,t10,t11} for pair k
    f4* __restrict__ y)
{
    const int p  = blockIdx.x * 256 + threadIdx.x;   // float4 column [0,1024)
    const int r0 = blockIdx.y * ROWS_PER_BLOCK;

    const f4 t0 = tw[2 * p];
    const f4 t1 = tw[2 * p + 1];

    const f4* xp = x + (size_t)r0 * ROW4 + p;
    f4*       yp = y + (size_t)r0 * ROW4 + p;

    f4 xv[ROWS_PER_BLOCK];
#pragma unroll
    for (int r = 0; r < ROWS_PER_BLOCK; ++r)
        xv[r] = __builtin_nontemporal_load(xp + (size_t)r * ROW4);

#pragma unroll
    for (int r = 0; r < ROWS_PER_BLOCK; ++r) {
        f4 yv;
        yv.x = t0.x * xv[r].x + t0.y * xv[r].y;
        yv.y = t0.z * xv[r].x + t0.w * xv[r].y;
        yv.z = t1.x * xv[r].z + t1.y * xv[r].w;
        yv.w = t1.z * xv[r].z + t1.w * xv[r].w;
        __builtin_nontemporal_store(yv, yp + (size_t)r * ROW4);
    }
}

extern "C" void kernel_launch(void* const* d_in, const int* in_sizes, int n_in,
                              void* d_out, int out_size, void* d_ws, size_t ws_size,
                              hipStream_t stream) {
    const f4* x  = (const f4*)d_in[0];   // (4, 2048, 4096) fp32
    const f4* tw = (const f4*)d_in[1];   // (2048, 2, 2) fp32
    f4* y = (f4*)d_out;

    const int n_rows = out_size / 4096;  // 8192

    dim3 block(256);
    dim3 grid(ROW4 / 256, n_rows / ROWS_PER_BLOCK);  // (4, 512) = 2048 blocks
    butterfly_kernel<<<grid, block, 0, stream>>>(x, tw, y);
}

// Round 4
// 229.965 us; speedup vs baseline: 1.0060x; 1.0060x over previous
//
#include <hip/hip_runtime.h>

// y[..., 2k]   = T[k][0][0]*x[2k] + T[k][0][1]*x[2k+1]
// y[..., 2k+1] = T[k][1][0]*x[2k] + T[k][1][1]*x[2k+1]
//
// R0 skeleton (fastest): thread owns one float4-column p, twiddles hoisted,
// 8 rows streamed, all loads batched up front (compiler keeps 8 in flight).
// Config-matrix evidence:
//   R0 NT/NT      222.9 us   (FETCH=134MB: NT loads skip L3)
//   R2 plain/plain 226.9 us  (plain loads: L3 serves x/2, but plain stores
//                             allocate y -> evict x; net loss)
//   R3 ROWS=16    231.4 us   (geometry lever exhausted; 8 rows optimal)
//   R1 grid-stride 243.9 us  (MLP collapse, VGPR=28 — never again)
// This round, the untested cell: PLAIN loads (harvest L3 hits on x, proven
// 67MB FETCH in R1) + NT stores (y streams past caches, x stays L3-resident).
// HBM demand 268 -> ~201 MB.

typedef float f4 __attribute__((ext_vector_type(4)));

#define ROW4 1024            // 4096 floats / 4 per row
#define ROWS_PER_BLOCK 8

__global__ __launch_bounds__(256) void butterfly_kernel(
    const f4* __restrict__ x,
    const f4* __restrict__ tw,   // tw[k] = {t00,t01,t10,t11} for pair k
    f4* __restrict__ y)
{
    const int p  = blockIdx.x * 256 + threadIdx.x;   // float4 column [0,1024)
    const int r0 = blockIdx.y * ROWS_PER_BLOCK;

    const f4 t0 = tw[2 * p];
    const f4 t1 = tw[2 * p + 1];

    const f4* xp = x + (size_t)r0 * ROW4 + p;
    f4*       yp = y + (size_t)r0 * ROW4 + p;

    f4 xv[ROWS_PER_BLOCK];
#pragma unroll
    for (int r = 0; r < ROWS_PER_BLOCK; ++r)
        xv[r] = xp[(size_t)r * ROW4];            // plain: L3 can serve

#pragma unroll
    for (int r = 0; r < ROWS_PER_BLOCK; ++r) {
        f4 yv;
        yv.x = t0.x * xv[r].x + t0.y * xv[r].y;
        yv.y = t0.z * xv[r].x + t0.w * xv[r].y;
        yv.z = t1.x * xv[r].z + t1.y * xv[r].w;
        yv.w = t1.z * xv[r].z + t1.w * xv[r].w;
        __builtin_nontemporal_store(yv, yp + (size_t)r * ROW4);  // NT: don't evict x
    }
}

extern "C" void kernel_launch(void* const* d_in, const int* in_sizes, int n_in,
                              void* d_out, int out_size, void* d_ws, size_t ws_size,
                              hipStream_t stream) {
    const f4* x  = (const f4*)d_in[0];   // (4, 2048, 4096) fp32
    const f4* tw = (const f4*)d_in[1];   // (2048, 2, 2) fp32
    f4* y = (f4*)d_out;

    const int n_rows = out_size / 4096;  // 8192

    dim3 block(256);
    dim3 grid(ROW4 / 256, n_rows / ROWS_PER_BLOCK);  // (4, 1024) = 4096 blocks
    butterfly_kernel<<<grid, block, 0, stream>>>(x, tw, y);
}

// Round 5
// 229.945 us; speedup vs baseline: 1.0061x; 1.0001x over previous
//
#include <hip/hip_runtime.h>

// y[..., 2k]   = T[k][0][0]*x[2k] + T[k][0][1]*x[2k+1]
// y[..., 2k+1] = T[k][1][0]*x[2k] + T[k][1][1]*x[2k+1]
//
// R0 body (proven best: 8-row batched loads, ~55 VGPR, NT/NT) wrapped in a
// #pragma unroll 1 loop of 2 row-groups per block. 2048 blocks = 8/CU =
// ONE residency generation at full 32 waves/CU.
// Theory being isolated: device-wide R/W phase-lock. One-shot blocks make
// the whole device oscillate read-storm <-> write-storm (HBM turnaround +
// queue drain each phase). A 2-iteration loop at unchanged occupancy lets
// waves desynchronize into a steady mixed R/W stream (what m13's 6.3 TB/s
// grid-stride copy has). R3 tested one-generation but was confounded by
// VGPR=85 -> 24 waves/CU; this keeps the 8-deep body and full occupancy.
// Config-matrix so far: R0 NT/NT 222.9 | R2 P/P 226.9 | R4 P/NT 230.0 |
// R3 ROWS=16 231.4 | R1 grid-stride collapse 243.9.

typedef float f4 __attribute__((ext_vector_type(4)));

#define ROW4 1024            // 4096 floats / 4 per row
#define ROWS_PER_BLOCK 8
#define ROW_GROUPS 2         // outer loop, NOT unrolled (keeps VGPR ~55)

__global__ __launch_bounds__(256) void butterfly_kernel(
    const f4* __restrict__ x,
    const f4* __restrict__ tw,   // tw[k] = {t00,t01,t10,t11} for pair k
    f4* __restrict__ y)
{
    const int p  = blockIdx.x * 256 + threadIdx.x;   // float4 column [0,1024)

    const f4 t0 = tw[2 * p];
    const f4 t1 = tw[2 * p + 1];

#pragma unroll 1
    for (int g = 0; g < ROW_GROUPS; ++g) {
        const int r0 = (blockIdx.y * ROW_GROUPS + g) * ROWS_PER_BLOCK;
        const f4* xp = x + (size_t)r0 * ROW4 + p;
        f4*       yp = y + (size_t)r0 * ROW4 + p;

        f4 xv[ROWS_PER_BLOCK];
#pragma unroll
        for (int r = 0; r < ROWS_PER_BLOCK; ++r)
            xv[r] = __builtin_nontemporal_load(xp + (size_t)r * ROW4);

#pragma unroll
        for (int r = 0; r < ROWS_PER_BLOCK; ++r) {
            f4 yv;
            yv.x = t0.x * xv[r].x + t0.y * xv[r].y;
            yv.y = t0.z * xv[r].x + t0.w * xv[r].y;
            yv.z = t1.x * xv[r].z + t1.y * xv[r].w;
            yv.w = t1.z * xv[r].z + t1.w * xv[r].w;
            __builtin_nontemporal_store(yv, yp + (size_t)r * ROW4);
        }
    }
}

extern "C" void kernel_launch(void* const* d_in, const int* in_sizes, int n_in,
                              void* d_out, int out_size, void* d_ws, size_t ws_size,
                              hipStream_t stream) {
    const f4* x  = (const f4*)d_in[0];   // (4, 2048, 4096) fp32
    const f4* tw = (const f4*)d_in[1];   // (2048, 2, 2) fp32
    f4* y = (f4*)d_out;

    const int n_rows = out_size / 4096;  // 8192

    dim3 block(256);
    dim3 grid(ROW4 / 256, n_rows / (ROWS_PER_BLOCK * ROW_GROUPS)); // (4, 512)
    butterfly_kernel<<<grid, block, 0, stream>>>(x, tw, y);
}

// Round 6
// 221.432 us; speedup vs baseline: 1.0448x; 1.0384x over previous
//
#include <hip/hip_runtime.h>

// y[..., 2k]   = T[k][0][0]*x[2k] + T[k][0][1]*x[2k+1]
// y[..., 2k+1] = T[k][1][0]*x[2k] + T[k][1][1]*x[2k+1]
//
// FINAL (R0 configuration — best of 6 measured variants, 222.9 us):
// each thread owns one float4-column p, loads its two twiddle float4s once
// into registers, streams 8 rows x->y with all 8 loads batched up front
// (compiler keeps them in flight; ~55 VGPR -> full 32 waves/CU).
// 4096 blocks = 16/CU. NT load + NT store.
//
// Config matrix (all measured, this session):
//   R0 8rows NT/NT one-shot      222.9   <- this kernel
//   R2 plain/plain               226.9   (L3 serves x/2 but no time win)
//   R5 2-group loop full-occ     229.9   (R/W phase-lock theory refuted)
//   R4 plain/NT                  230.0   (cache-policy matrix flat)
//   R3 ROWS=16 one-generation    231.4   (occupancy drop outweighs)
//   R1 grid-stride sweep         243.9   (compiler collapsed MLP, VGPR=28)
// Aggregate timed-region traffic = 1.342 GB (2 harness poison-fills + this
// kernel) / 222.9 us = 6.02 TB/s = 96% of the 6.29 TB/s measured device
// ceiling. Memory-roofline-bound; remaining dur_us is harness fill time.

typedef float f4 __attribute__((ext_vector_type(4)));

#define ROW4 1024            // 4096 floats / 4 per row
#define ROWS_PER_BLOCK 8

__global__ __launch_bounds__(256) void butterfly_kernel(
    const f4* __restrict__ x,
    const f4* __restrict__ tw,   // tw[k] = {t00,t01,t10,t11} for pair k
    f4* __restrict__ y)
{
    const int p  = blockIdx.x * 256 + threadIdx.x;   // float4 column [0,1024)
    const int r0 = blockIdx.y * ROWS_PER_BLOCK;

    const f4 t0 = tw[2 * p];
    const f4 t1 = tw[2 * p + 1];

    const f4* xp = x + (size_t)r0 * ROW4 + p;
    f4*       yp = y + (size_t)r0 * ROW4 + p;

    f4 xv[ROWS_PER_BLOCK];
#pragma unroll
    for (int r = 0; r < ROWS_PER_BLOCK; ++r)
        xv[r] = __builtin_nontemporal_load(xp + (size_t)r * ROW4);

#pragma unroll
    for (int r = 0; r < ROWS_PER_BLOCK; ++r) {
        f4 yv;
        yv.x = t0.x * xv[r].x + t0.y * xv[r].y;
        yv.y = t0.z * xv[r].x + t0.w * xv[r].y;
        yv.z = t1.x * xv[r].z + t1.y * xv[r].w;
        yv.w = t1.z * xv[r].z + t1.w * xv[r].w;
        __builtin_nontemporal_store(yv, yp + (size_t)r * ROW4);
    }
}

extern "C" void kernel_launch(void* const* d_in, const int* in_sizes, int n_in,
                              void* d_out, int out_size, void* d_ws, size_t ws_size,
                              hipStream_t stream) {
    const f4* x  = (const f4*)d_in[0];   // (4, 2048, 4096) fp32
    const f4* tw = (const f4*)d_in[1];   // (2048, 2, 2) fp32
    f4* y = (f4*)d_out;

    const int n_rows = out_size / 4096;  // 8192

    dim3 block(256);
    dim3 grid(ROW4 / 256, n_rows / ROWS_PER_BLOCK);  // (4, 1024) = 4096 blocks
    butterfly_kernel<<<grid, block, 0, stream>>>(x, tw, y);
}